// Round 3
// baseline (6334.003 us; speedup 1.0000x reference)
//
#include <hip/hip_runtime.h>
#include <stdint.h>

// DecoderRNN: B=256, NSTEPS=128, I=128, H=1024, V=1024, teacher-forced GRU.
// Round 3: single persistent kernel for all 128 steps.
//   precompute: E = relu(embed_w)@W_ih[:,:H]^T ; Zih2 = z@W_ih[:,H:]^T + b_ih (+b_hh for r,z)
//               Zout = z@out_w[:,H:]^T + out_b ; h0 = z@z2h_w^T + z2h_b
//   decoder_k: 256 blocks (1/CU), loop s=0..128 with device-atomic grid barrier.
//     block (rB,c): rows 64rB..+63, cols 16c..+15 (same 16 cols for all 3 gates + V).
//     W_hh gate-r slice in REGISTERS (32 bf16x8), gates z,n in LDS (persistent).
//     Per step: stage h_s chunks (dbuf) -> GRU MFMA (h_{s+1}) + OUT MFMA (o_{s-1})
//     sharing the same A fragments. h exchanged via global bf16 ping-pong.

#define NSTEP 128

typedef unsigned short u16;
typedef unsigned int u32;
typedef __attribute__((ext_vector_type(8))) short bf16x8;
typedef __attribute__((ext_vector_type(4))) float f32x4;

typedef __attribute__((address_space(3))) void lds_void;
typedef const __attribute__((address_space(1))) void glb_void;
#define GLD16(g, l) __builtin_amdgcn_global_load_lds((glb_void*)(g), (lds_void*)(l), 16, 0, 0)

__device__ __forceinline__ u16 f2bf(float f) {
    u32 u = __float_as_uint(f);
    u = (u + 0x7FFFu + ((u >> 16) & 1u)) >> 16;
    return (u16)u;
}

// ---- elementwise fp32 -> bf16 cast (1024 columns per row) ------------------
__global__ void cast_k(const float* __restrict__ src, int ld, int off, int relu,
                       u16* __restrict__ dst, int n) {
    for (int i = blockIdx.x * blockDim.x + threadIdx.x; i < n; i += gridDim.x * blockDim.x) {
        int row = i >> 10, col = i & 1023;
        float v = src[(long)row * ld + off + col];
        if (relu) v = fmaxf(v, 0.f);
        dst[i] = f2bf(v);
    }
}

// ---- small fp32 GEMM: C[b][n] = z[b]·W[n, off:off+128] + bias[n] (+bias2) --
__global__ void smallgemm_k(const float* __restrict__ z, const float* __restrict__ W,
                            int ldw, int off, const float* __restrict__ bias,
                            const float* __restrict__ bias2, int n2max,
                            float* __restrict__ C, u16* __restrict__ Cbf, int N) {
    int n = blockIdx.x;
    int b = threadIdx.x;
    float acc = bias[n] + ((bias2 && n < n2max) ? bias2[n] : 0.f);
    const float* zr = z + b * 128;
    const float* wr = W + (long)n * ldw + off;
#pragma unroll 8
    for (int k = 0; k < 128; ++k) acc += zr[k] * wr[k];
    C[b * N + n] = acc;
    if (Cbf) Cbf[b * N + n] = f2bf(acc);
}

// ---- E table GEMM: E[v][n] = relu(embed)[v]·Wihh[n]  (M=1024,N=3072,K=1024)
__global__ __launch_bounds__(256) void egemm_k(const u16* __restrict__ A,
                                               const u16* __restrict__ W,
                                               float* __restrict__ C) {
    __shared__ __align__(16) u16 lds[2][160 * 64];
    int tid = threadIdx.x, lane = tid & 63, wv = tid >> 6;
    int r0 = (blockIdx.x & 31) * 32;
    int n0 = (blockIdx.x >> 5) * 128;

    f32x4 acc[2][2];
#pragma unroll
    for (int m = 0; m < 2; ++m)
#pragma unroll
        for (int n = 0; n < 2; ++n) acc[m][n] = (f32x4){0.f, 0.f, 0.f, 0.f};

    auto stage = [&](int k0, int bufi) {
#pragma unroll
        for (int r = 0; r < 5; ++r) {
            int L = r * 256 + tid;
            int row = L >> 3;
            int c4 = (L & 7) ^ (row & 7);
            const u16* src = (row < 32)
                                 ? A + (long)(r0 + row) * 1024 + k0 + c4 * 8
                                 : W + (long)(n0 + row - 32) * 1024 + k0 + c4 * 8;
            GLD16(src, &lds[bufi][L * 8]);
        }
    };
    stage(0, 0);
    stage(64, 1);
    for (int it = 0; it < 16; ++it) {
        if (it < 15) asm volatile("s_waitcnt vmcnt(5)" ::: "memory");
        else         asm volatile("s_waitcnt vmcnt(0)" ::: "memory");
        __builtin_amdgcn_s_barrier();
        const char* base = (const char*)&lds[it & 1][0];
        bf16x8 af[2][2], bfr[2][2];
#pragma unroll
        for (int ks = 0; ks < 2; ++ks)
#pragma unroll
            for (int q = 0; q < 2; ++q) {
                int kb = ks * 64 + ((lane >> 4) << 4);
                int rowa = q * 16 + (lane & 15);
                af[ks][q] = *(const bf16x8*)(base + rowa * 128 + (kb ^ ((rowa & 7) << 4)));
                int rowb = 32 + wv * 32 + q * 16 + (lane & 15);
                bfr[ks][q] = *(const bf16x8*)(base + rowb * 128 + (kb ^ ((rowb & 7) << 4)));
            }
#pragma unroll
        for (int ks = 0; ks < 2; ++ks)
#pragma unroll
            for (int m = 0; m < 2; ++m)
#pragma unroll
                for (int n = 0; n < 2; ++n)
                    acc[m][n] = __builtin_amdgcn_mfma_f32_16x16x32_bf16(af[ks][m], bfr[ks][n],
                                                                        acc[m][n], 0, 0, 0);
        asm volatile("s_waitcnt lgkmcnt(0)" ::: "memory");
        __builtin_amdgcn_s_barrier();
        if (it + 2 < 16) stage((it + 2) * 64, it & 1);
    }
#pragma unroll
    for (int m = 0; m < 2; ++m)
#pragma unroll
        for (int n = 0; n < 2; ++n)
#pragma unroll
            for (int r = 0; r < 4; ++r) {
                int row = r0 + m * 16 + ((lane >> 4) << 2) + r;
                int col = n0 + wv * 32 + n * 16 + (lane & 15);
                C[(long)row * 3072 + col] = acc[m][n][r];
            }
}

// ---- persistent decoder ----------------------------------------------------
// LDS layout (bytes):
//   [0, 65536)        W12: gates z,n  [32 rows][1024 k], row stride 2048 B
//   [65536, 106496)   dbuf: 2 x 20480 B chunks: [80 rows][128 k], row stride 256 B
//                     rows 0..63 = h_s tile, rows 64..79 = Wout tile
//   (startup: gate-r slice [16][1024] temporarily at 65536, read into regs)
__global__ __launch_bounds__(256, 1) void decoder_k(
    const u16* __restrict__ Whh,    // [3072][1024] bf16
    const u16* __restrict__ Wout,   // [1024][1024] bf16
    const float* __restrict__ E,    // [1024][3072]
    const float* __restrict__ Zih2, // [256][3072]  (b_ih folded; +b_hh for r,z)
    const float* __restrict__ Zout, // [256][1024]  (out_b folded)
    const float* __restrict__ bhh,  // [3072]
    const int* __restrict__ toks,   // [128][256]
    const float* __restrict__ h0f,  // [256][1024] fp32
    u16* __restrict__ Hx,           // [2][256][1024] bf16 ping-pong
    float* __restrict__ out,        // [256][128][1024]
    u32* __restrict__ bar) {
    __shared__ __align__(16) char L[106496];
    const int tid = threadIdx.x, lane = tid & 63, wv = tid >> 6;
    const int bid = blockIdx.x;
    const int rB = bid >> 6; // rows rB*64..+63
    const int c = bid & 63;  // cols c*16..+15

    // ---- startup staging: gate-r slice -> tmp (dbuf region), gates z,n -> W12
#pragma unroll
    for (int r = 0; r < 8; ++r) {
        int l = r * 256 + tid, row = l >> 7, ck = (l & 127) ^ (row & 15);
        GLD16(Whh + (long)(c * 16 + row) * 1024 + ck * 8, &L[65536 + l * 16]);
    }
#pragma unroll
    for (int r = 0; r < 16; ++r) {
        int l = r * 256 + tid, row = l >> 7, ck = (l & 127) ^ (row & 15);
        GLD16(Whh + (long)((1 + (row >> 4)) * 1024 + c * 16 + (row & 15)) * 1024 + ck * 8,
              &L[l * 16]);
    }
    asm volatile("s_waitcnt vmcnt(0)" ::: "memory");
    __builtin_amdgcn_s_barrier();
    bf16x8 w0[32]; // gate-r B-fragments, [it*4+ks], persistent in VGPRs
#pragma unroll
    for (int it = 0; it < 8; ++it)
#pragma unroll
        for (int ks = 0; ks < 4; ++ks) {
            int row = lane & 15, kc = it * 16 + ks * 4 + (lane >> 4);
            w0[it * 4 + ks] = *(const bf16x8*)(L + 65536 + row * 2048 + ((kc ^ row) << 4));
        }
    asm volatile("s_waitcnt lgkmcnt(0)" ::: "memory");
    __builtin_amdgcn_s_barrier();

    // ---- per-thread step-invariant state
    const int bbase = rB * 64 + wv * 16 + ((lane >> 4) << 2); // 4 rows bbase..+3
    const int j = c * 16 + (lane & 15);
    const float bhn = bhh[2048 + j];
    float hprev[4], zi0[4], zi1[4], zi2[4], zo[4];
#pragma unroll
    for (int r = 0; r < 4; ++r) {
        int b = bbase + r;
        hprev[r] = h0f[b * 1024 + j];
        zi0[r] = Zih2[(long)b * 3072 + j];
        zi1[r] = Zih2[(long)b * 3072 + 1024 + j];
        zi2[r] = Zih2[(long)b * 3072 + 2048 + j];
        zo[r] = Zout[b * 1024 + j];
    }

    for (int s = 0; s <= NSTEP; ++s) {
        // token + E prefetch (consumed in epilogue; latency hidden by K-loop)
        float e0[4], e1[4], e2[4];
#pragma unroll
        for (int r = 0; r < 4; ++r) {
            int b = bbase + r;
            int tok = (s == 0) ? 0 : toks[(s - 1) * 256 + b];
            e0[r] = E[(long)tok * 3072 + j];
            e1[r] = E[(long)tok * 3072 + 1024 + j];
            e2[r] = E[(long)tok * 3072 + 2048 + j];
        }
        const u16* hsrc = Hx + (size_t)(s & 1) * 262144;

        auto stage = [&](int ch) {
            char* dst = L + 65536 + (ch & 1) * 20480;
            int k0 = ch * 128;
#pragma unroll
            for (int r = 0; r < 5; ++r) {
                int l = r * 256 + tid, row = l >> 4, ck = (l & 15) ^ (row & 15);
                const u16* src = (row < 64)
                                     ? hsrc + (long)(rB * 64 + row) * 1024 + k0 + ck * 8
                                     : Wout + (long)(c * 16 + row - 64) * 1024 + k0 + ck * 8;
                GLD16(src, dst + l * 16);
            }
        };
        stage(0);
        stage(1);

        f32x4 a0 = {0.f, 0.f, 0.f, 0.f}, a1 = a0, a2 = a0, aO = a0;
#pragma unroll
        for (int it = 0; it < 8; ++it) {
            if (it < 7) asm volatile("s_waitcnt vmcnt(5)" ::: "memory");
            else        asm volatile("s_waitcnt vmcnt(0)" ::: "memory");
            __builtin_amdgcn_s_barrier();
            const char* Ab = L + 65536 + (it & 1) * 20480;
            bf16x8 af[4];
#pragma unroll
            for (int ks = 0; ks < 4; ++ks) {
                int row = wv * 16 + (lane & 15), kc = ks * 4 + (lane >> 4);
                af[ks] = *(const bf16x8*)(Ab + row * 256 + ((kc ^ (row & 15)) << 4));
            }
#pragma unroll
            for (int ks = 0; ks < 4; ++ks) // gate r from registers
                a0 = __builtin_amdgcn_mfma_f32_16x16x32_bf16(af[ks], w0[it * 4 + ks], a0, 0, 0, 0);
#pragma unroll
            for (int ks = 0; ks < 4; ++ks) { // gate z from W12 LDS
                int row = lane & 15, kc = it * 16 + ks * 4 + (lane >> 4);
                bf16x8 wg = *(const bf16x8*)(L + row * 2048 + ((kc ^ row) << 4));
                a1 = __builtin_amdgcn_mfma_f32_16x16x32_bf16(af[ks], wg, a1, 0, 0, 0);
            }
#pragma unroll
            for (int ks = 0; ks < 4; ++ks) { // gate n from W12 LDS
                int row = 16 + (lane & 15), kc = it * 16 + ks * 4 + (lane >> 4);
                bf16x8 wg = *(const bf16x8*)(L + row * 2048 + ((kc ^ (row & 15)) << 4));
                a2 = __builtin_amdgcn_mfma_f32_16x16x32_bf16(af[ks], wg, a2, 0, 0, 0);
            }
#pragma unroll
            for (int ks = 0; ks < 4; ++ks) { // OUT from dbuf rows 64..79
                int row = 64 + (lane & 15), kc = ks * 4 + (lane >> 4);
                bf16x8 wo = *(const bf16x8*)(Ab + row * 256 + ((kc ^ (row & 15)) << 4));
                aO = __builtin_amdgcn_mfma_f32_16x16x32_bf16(af[ks], wo, aO, 0, 0, 0);
            }
            asm volatile("s_waitcnt lgkmcnt(0)" ::: "memory");
            __builtin_amdgcn_s_barrier();
            if (it < 6) stage(it + 2);
        }

        if (s < NSTEP) { // GRU epilogue -> h_{s+1}
            u16* hdst = Hx + (size_t)((s + 1) & 1) * 262144;
#pragma unroll
            for (int r = 0; r < 4; ++r) {
                int b = bbase + r;
                float rg = 1.f / (1.f + expf(-(e0[r] + zi0[r] + a0[r])));
                float zg = 1.f / (1.f + expf(-(e1[r] + zi1[r] + a1[r])));
                float nn = tanhf(e2[r] + zi2[r] + rg * (a2[r] + bhn));
                float hv = (1.f - zg) * nn + zg * hprev[r];
                hprev[r] = hv;
                hdst[b * 1024 + j] = f2bf(hv);
            }
        }
        if (s >= 1) { // OUT epilogue -> o_{s-1}
#pragma unroll
            for (int r = 0; r < 4; ++r)
                out[(long)(bbase + r) * 131072 + (long)(s - 1) * 1024 + j] = aO[r] + zo[r];
        }
        if (s < NSTEP) { // grid barrier (device-scope), monotone counter
            __threadfence();
            __syncthreads();
            if (tid == 0) {
                __hip_atomic_fetch_add(bar, 1u, __ATOMIC_ACQ_REL, __HIP_MEMORY_SCOPE_AGENT);
                u32 tgt = 256u * (u32)(s + 1);
                while (__hip_atomic_load(bar, __ATOMIC_ACQUIRE, __HIP_MEMORY_SCOPE_AGENT) < tgt)
                    __builtin_amdgcn_s_sleep(2);
                __threadfence();
            }
            __syncthreads();
        }
    }
}

extern "C" void kernel_launch(void* const* d_in, const int* in_sizes, int n_in,
                              void* d_out, int out_size, void* d_ws, size_t ws_size,
                              hipStream_t stream) {
    const float* z = (const float*)d_in[0];
    const int* toks = (const int*)d_in[1];
    const float* embed_w = (const float*)d_in[3];
    const float* z2h_w = (const float*)d_in[4];
    const float* z2h_b = (const float*)d_in[5];
    const float* w_ih = (const float*)d_in[6];
    const float* b_ih = (const float*)d_in[7];
    const float* w_hh = (const float*)d_in[8];
    const float* b_hh = (const float*)d_in[9];
    const float* out_w = (const float*)d_in[10];
    const float* out_b = (const float*)d_in[11];
    float* out = (float*)d_out;

    char* ws = (char*)d_ws;
    size_t off = 0;
    auto alloc = [&](size_t bytes) {
        char* p = ws + off;
        off += (bytes + 255) & ~(size_t)255;
        return p;
    };
    u16* Whh_bf = (u16*)alloc(3072ull * 1024 * 2);
    u16* Wout_bf = (u16*)alloc(1024ull * 1024 * 2);
    u16* Wihh_bf = (u16*)alloc(3072ull * 1024 * 2);
    u16* Emb_bf = (u16*)alloc(1024ull * 1024 * 2);
    float* E = (float*)alloc(1024ull * 3072 * 4);
    float* Zih = (float*)alloc(256ull * 3072 * 4);
    float* Zout = (float*)alloc(256ull * 1024 * 4);
    float* hf = (float*)alloc(256ull * 1024 * 4);
    u16* Hx = (u16*)alloc(2ull * 256 * 1024 * 2);
    u32* bar = (u32*)alloc(256);
    // total ws use ~34.5 MB

    hipMemsetAsync(bar, 0, 4, stream);
    cast_k<<<2048, 256, 0, stream>>>(w_hh, 1024, 0, 0, Whh_bf, 3072 * 1024);
    cast_k<<<2048, 256, 0, stream>>>(out_w, 1152, 0, 0, Wout_bf, 1024 * 1024);
    cast_k<<<2048, 256, 0, stream>>>(w_ih, 1152, 0, 0, Wihh_bf, 3072 * 1024);
    cast_k<<<1024, 256, 0, stream>>>(embed_w, 1024, 0, 1, Emb_bf, 1024 * 1024);
    smallgemm_k<<<1024, 256, 0, stream>>>(z, z2h_w, 128, 0, z2h_b, nullptr, 0, hf, Hx, 1024);
    smallgemm_k<<<3072, 256, 0, stream>>>(z, w_ih, 1152, 1024, b_ih, b_hh, 2048, Zih, nullptr, 3072);
    smallgemm_k<<<1024, 256, 0, stream>>>(z, out_w, 1152, 1024, out_b, nullptr, 0, Zout, nullptr, 1024);
    egemm_k<<<768, 256, 0, stream>>>(Emb_bf, Wihh_bf, E);

    decoder_k<<<256, 256, 0, stream>>>(Whh_bf, Wout_bf, E, Zih, Zout, b_hh, toks, hf, Hx, out,
                                       bar);
}

// Round 6
// 2343.176 us; speedup vs baseline: 2.7032x; 2.7032x over previous
//
#include <hip/hip_runtime.h>
#include <stdint.h>

// DecoderRNN: B=256, NSTEPS=128, I=128, H=1024, V=1024, teacher-forced GRU.
// Round 6: persistent weight-stationary kernel; r3-proven conservative vmcnt
// dataflow (E in epilogue); per-row-group flag barrier (64 blocks/group,
// release store + relaxed poll + single acquire-inv).
//   precompute: E = relu(embed_w)@W_ih[:,:H]^T ; Zih2 = z@W_ih[:,H:]^T + b_ih (+b_hh r,z)
//               Zout = z@out_w[:,H:]^T + out_b ; h0 = z@z2h_w^T + z2h_b
//   decoder_k: 256 blocks (1/CU), loop s=0..128.
//     block (rB,c): batch rows 64rB..+63, cols 16c..+15 (all 3 gates + V).
//     W_hh gate-r in REGISTERS (32 bf16x8); gates z,n + Wout slice in LDS
//     persistent. Per step: stage only h_s (dbuf) -> 16 MFMA x 8 iters -> epilogue.

#define NSTEP 128

typedef unsigned short u16;
typedef unsigned int u32;
typedef __attribute__((ext_vector_type(8))) short bf16x8;
typedef __attribute__((ext_vector_type(4))) float f32x4;

typedef __attribute__((address_space(3))) void lds_void;
typedef const __attribute__((address_space(1))) void glb_void;
#define GLD16(g, l) __builtin_amdgcn_global_load_lds((glb_void*)(g), (lds_void*)(l), 16, 0, 0)
#define CFENCE() asm volatile("" ::: "memory")

__device__ __forceinline__ u16 f2bf(float f) {
    u32 u = __float_as_uint(f);
    u = (u + 0x7FFFu + ((u >> 16) & 1u)) >> 16;
    return (u16)u;
}

// ---- elementwise fp32 -> bf16 cast (1024 columns per row) ------------------
__global__ void cast_k(const float* __restrict__ src, int ld, int off, int relu,
                       u16* __restrict__ dst, int n) {
    for (int i = blockIdx.x * blockDim.x + threadIdx.x; i < n; i += gridDim.x * blockDim.x) {
        int row = i >> 10, col = i & 1023;
        float v = src[(long)row * ld + off + col];
        if (relu) v = fmaxf(v, 0.f);
        dst[i] = f2bf(v);
    }
}

// ---- small fp32 GEMM: C[b][n] = z[b]·W[n, off:off+128] + bias[n] (+bias2) --
__global__ void smallgemm_k(const float* __restrict__ z, const float* __restrict__ W,
                            int ldw, int off, const float* __restrict__ bias,
                            const float* __restrict__ bias2, int n2max,
                            float* __restrict__ C, u16* __restrict__ Cbf, int N) {
    int n = blockIdx.x;
    int b = threadIdx.x;
    float acc = bias[n] + ((bias2 && n < n2max) ? bias2[n] : 0.f);
    const float* zr = z + b * 128;
    const float* wr = W + (long)n * ldw + off;
#pragma unroll 8
    for (int k = 0; k < 128; ++k) acc += zr[k] * wr[k];
    C[b * N + n] = acc;
    if (Cbf) Cbf[b * N + n] = f2bf(acc);
}

// ---- E table GEMM: E[v][n] = relu(embed)[v]·Wihh[n]  (M=1024,N=3072,K=1024)
__global__ __launch_bounds__(256) void egemm_k(const u16* __restrict__ A,
                                               const u16* __restrict__ W,
                                               float* __restrict__ C) {
    __shared__ __align__(16) u16 lds[2][160 * 64];
    int tid = threadIdx.x, lane = tid & 63, wv = tid >> 6;
    int r0 = (blockIdx.x & 31) * 32;
    int n0 = (blockIdx.x >> 5) * 128;

    f32x4 acc[2][2];
#pragma unroll
    for (int m = 0; m < 2; ++m)
#pragma unroll
        for (int n = 0; n < 2; ++n) acc[m][n] = (f32x4){0.f, 0.f, 0.f, 0.f};

    auto stage = [&](int k0, int bufi) {
#pragma unroll
        for (int r = 0; r < 5; ++r) {
            int L = r * 256 + tid;
            int row = L >> 3;
            int c4 = (L & 7) ^ (row & 7);
            const u16* src = (row < 32)
                                 ? A + (long)(r0 + row) * 1024 + k0 + c4 * 8
                                 : W + (long)(n0 + row - 32) * 1024 + k0 + c4 * 8;
            GLD16(src, &lds[bufi][L * 8]);
        }
    };
    stage(0, 0);
    stage(64, 1);
    for (int it = 0; it < 16; ++it) {
        if (it < 15) asm volatile("s_waitcnt vmcnt(5)" ::: "memory");
        else         asm volatile("s_waitcnt vmcnt(0)" ::: "memory");
        __builtin_amdgcn_s_barrier();
        const char* base = (const char*)&lds[it & 1][0];
        bf16x8 af[2][2], bfr[2][2];
#pragma unroll
        for (int ks = 0; ks < 2; ++ks)
#pragma unroll
            for (int q = 0; q < 2; ++q) {
                int kb = ks * 64 + ((lane >> 4) << 4);
                int rowa = q * 16 + (lane & 15);
                af[ks][q] = *(const bf16x8*)(base + rowa * 128 + (kb ^ ((rowa & 7) << 4)));
                int rowb = 32 + wv * 32 + q * 16 + (lane & 15);
                bfr[ks][q] = *(const bf16x8*)(base + rowb * 128 + (kb ^ ((rowb & 7) << 4)));
            }
#pragma unroll
        for (int ks = 0; ks < 2; ++ks)
#pragma unroll
            for (int m = 0; m < 2; ++m)
#pragma unroll
                for (int n = 0; n < 2; ++n)
                    acc[m][n] = __builtin_amdgcn_mfma_f32_16x16x32_bf16(af[ks][m], bfr[ks][n],
                                                                        acc[m][n], 0, 0, 0);
        asm volatile("s_waitcnt lgkmcnt(0)" ::: "memory");
        __builtin_amdgcn_s_barrier();
        if (it + 2 < 16) stage((it + 2) * 64, it & 1);
    }
#pragma unroll
    for (int m = 0; m < 2; ++m)
#pragma unroll
        for (int n = 0; n < 2; ++n)
#pragma unroll
            for (int r = 0; r < 4; ++r) {
                int row = r0 + m * 16 + ((lane >> 4) << 2) + r;
                int col = n0 + wv * 32 + n * 16 + (lane & 15);
                C[(long)row * 3072 + col] = acc[m][n][r];
            }
}

// ---- persistent decoder ----------------------------------------------------
// LDS layout (bytes), 131072 total:
//   [0, 65536)        W12: gates z,n  [32 rows][1024 k], row stride 2048 B
//   [65536, 98304)    WoutL: [16 rows][1024 k], row stride 2048 B (persistent)
//   [98304, 131072)   dbuf: 2 x 16384 B: [64 rows][128 k], row stride 256 B
//   (startup: gate-r slice [16][1024] temporarily in dbuf region -> regs)
__global__ __launch_bounds__(256, 1) void decoder_k(
    const u16* __restrict__ Whh,    // [3072][1024] bf16
    const u16* __restrict__ Wout,   // [1024][1024] bf16
    const float* __restrict__ E,    // [1024][3072]
    const float* __restrict__ Zih2, // [256][3072]  (b_ih folded; +b_hh for r,z)
    const float* __restrict__ Zout, // [256][1024]  (out_b folded)
    const float* __restrict__ bhh,  // [3072]
    const int* __restrict__ toks,   // [128][256]
    const float* __restrict__ h0f,  // [256][1024] fp32
    u16* __restrict__ Hx,           // [2][256][1024] bf16 ping-pong
    float* __restrict__ out,        // [256][128][1024]
    u32* __restrict__ flags) {      // [256] per-block step flags
    __shared__ __align__(16) char L[131072];
    const int tid = threadIdx.x, lane = tid & 63, wv = tid >> 6;
    const int bid = blockIdx.x;
    const int rB = bid >> 6; // rows rB*64..+63
    const int c = bid & 63;  // cols c*16..+15

    // ---- startup staging: gate-r -> tmp(dbuf), gates z,n -> W12, Wout -> WoutL
#pragma unroll
    for (int r = 0; r < 8; ++r) {
        int l = r * 256 + tid, row = l >> 7, ck = (l & 127) ^ (row & 15);
        GLD16(Whh + (long)(c * 16 + row) * 1024 + ck * 8, &L[98304 + l * 16]);
    }
#pragma unroll
    for (int r = 0; r < 16; ++r) {
        int l = r * 256 + tid, row = l >> 7, ck = (l & 127) ^ (row & 15);
        GLD16(Whh + (long)((1 + (row >> 4)) * 1024 + c * 16 + (row & 15)) * 1024 + ck * 8,
              &L[l * 16]);
    }
#pragma unroll
    for (int r = 0; r < 8; ++r) {
        int l = r * 256 + tid, row = l >> 7, ck = (l & 127) ^ (row & 15);
        GLD16(Wout + (long)(c * 16 + row) * 1024 + ck * 8, &L[65536 + l * 16]);
    }
    asm volatile("s_waitcnt vmcnt(0)" ::: "memory");
    __builtin_amdgcn_s_barrier();
    bf16x8 w0[32]; // gate-r B-fragments, [it*4+ks], persistent in VGPRs
#pragma unroll
    for (int it = 0; it < 8; ++it)
#pragma unroll
        for (int ks = 0; ks < 4; ++ks) {
            int row = lane & 15, kc = it * 16 + ks * 4 + (lane >> 4);
            w0[it * 4 + ks] = *(const bf16x8*)(L + 98304 + row * 2048 + ((kc ^ row) << 4));
        }
    asm volatile("s_waitcnt lgkmcnt(0)" ::: "memory");
    __builtin_amdgcn_s_barrier();

    // ---- per-thread step-invariant state
    const int bbase = rB * 64 + wv * 16 + ((lane >> 4) << 2); // 4 rows bbase..+3
    const int j = c * 16 + (lane & 15);
    const float bhn = bhh[2048 + j];
    float hprev[4], zi0[4], zi1[4], zi2[4], zo[4];
#pragma unroll
    for (int r = 0; r < 4; ++r) {
        int b = bbase + r;
        hprev[r] = h0f[b * 1024 + j];
        zi0[r] = Zih2[(long)b * 3072 + j];
        zi1[r] = Zih2[(long)b * 3072 + 1024 + j];
        zi2[r] = Zih2[(long)b * 3072 + 2048 + j];
        zo[r] = Zout[b * 1024 + j];
    }

    for (int s = 0; s <= NSTEP; ++s) {
        // tokens (consumed in epilogue); pinned before stages
        int tok[4];
#pragma unroll
        for (int r = 0; r < 4; ++r)
            tok[r] = (s == 0) ? 0 : toks[(s - 1) * 256 + bbase + r];
        CFENCE();

        const u16* hsrc = Hx + (size_t)(s & 1) * 262144;
        auto stage = [&](int ch) {
            char* dst = L + 98304 + (ch & 1) * 16384;
            int k0 = ch * 128;
#pragma unroll
            for (int r = 0; r < 4; ++r) {
                int l = r * 256 + tid, row = l >> 4, ck = (l & 15) ^ (row & 15);
                GLD16(hsrc + (long)(rB * 64 + row) * 1024 + k0 + ck * 8, dst + l * 16);
            }
        };
        stage(0);
        stage(1);
        CFENCE();

        f32x4 a0 = {0.f, 0.f, 0.f, 0.f}, a1 = a0, a2 = a0, aO = a0;
#pragma unroll
        for (int it = 0; it < 8; ++it) {
            // conservative schedule: leave exactly next-stage (4 loads) in flight
            if (it < 7) asm volatile("s_waitcnt vmcnt(4)" ::: "memory");
            else        asm volatile("s_waitcnt vmcnt(0)" ::: "memory");
            __builtin_amdgcn_s_barrier();
            const char* Ab = L + 98304 + (it & 1) * 16384;
            bf16x8 af[4];
#pragma unroll
            for (int ks = 0; ks < 4; ++ks) {
                int row = wv * 16 + (lane & 15), kc = ks * 4 + (lane >> 4);
                af[ks] = *(const bf16x8*)(Ab + row * 256 + ((kc ^ (row & 15)) << 4));
            }
#pragma unroll
            for (int ks = 0; ks < 4; ++ks) // gate r from registers
                a0 = __builtin_amdgcn_mfma_f32_16x16x32_bf16(af[ks], w0[it * 4 + ks], a0, 0, 0, 0);
#pragma unroll
            for (int ks = 0; ks < 4; ++ks) { // gate z from W12
                int row = lane & 15, kc = it * 16 + ks * 4 + (lane >> 4);
                bf16x8 wg = *(const bf16x8*)(L + row * 2048 + ((kc ^ row) << 4));
                a1 = __builtin_amdgcn_mfma_f32_16x16x32_bf16(af[ks], wg, a1, 0, 0, 0);
            }
#pragma unroll
            for (int ks = 0; ks < 4; ++ks) { // gate n from W12
                int row = 16 + (lane & 15), kc = it * 16 + ks * 4 + (lane >> 4);
                bf16x8 wg = *(const bf16x8*)(L + row * 2048 + ((kc ^ (row & 15)) << 4));
                a2 = __builtin_amdgcn_mfma_f32_16x16x32_bf16(af[ks], wg, a2, 0, 0, 0);
            }
#pragma unroll
            for (int ks = 0; ks < 4; ++ks) { // OUT from WoutL (persistent)
                int row = lane & 15, kc = it * 16 + ks * 4 + (lane >> 4);
                bf16x8 wo = *(const bf16x8*)(L + 65536 + row * 2048 + ((kc ^ row) << 4));
                aO = __builtin_amdgcn_mfma_f32_16x16x32_bf16(af[ks], wo, aO, 0, 0, 0);
            }
            asm volatile("s_waitcnt lgkmcnt(0)" ::: "memory");
            __builtin_amdgcn_s_barrier();
            if (it < 6) stage(it + 2);
        }

        if (s < NSTEP) { // GRU epilogue -> h_{s+1} (E read here, r3-proven)
            u16* hdst = Hx + (size_t)((s + 1) & 1) * 262144;
#pragma unroll
            for (int r = 0; r < 4; ++r) {
                int b = bbase + r;
                long eb = (long)tok[r] * 3072 + j;
                float rg = 1.f / (1.f + expf(-(E[eb] + zi0[r] + a0[r])));
                float zg = 1.f / (1.f + expf(-(E[eb + 1024] + zi1[r] + a1[r])));
                float nn = tanhf(E[eb + 2048] + zi2[r] + rg * (a2[r] + bhn));
                float hv = (1.f - zg) * nn + zg * hprev[r];
                hprev[r] = hv;
                hdst[b * 1024 + j] = f2bf(hv);
            }
        }
        if (s >= 1) { // OUT epilogue -> o_{s-1}
#pragma unroll
            for (int r = 0; r < 4; ++r)
                out[(long)(bbase + r) * 131072 + (long)(s - 1) * 1024 + j] = aO[r] + zo[r];
        }
        if (s < NSTEP) {
            // per-row-group barrier: 64 blocks sharing rB exchange h rows
            asm volatile("s_waitcnt vmcnt(0)" ::: "memory"); // each wave drains its stores
            __syncthreads();
            if (tid < 64) { // wave 0
                if (tid == 0) {
                    __builtin_amdgcn_fence(__ATOMIC_RELEASE, "agent"); // wb L2 -> coherent pt
                    __hip_atomic_store(&flags[bid], (u32)(s + 1), __ATOMIC_RELAXED,
                                       __HIP_MEMORY_SCOPE_AGENT);
                }
                const u32 tgt = (u32)(s + 1);
                const u32* gf = flags + (rB << 6);
                while (true) {
                    u32 v = __hip_atomic_load(&gf[tid], __ATOMIC_RELAXED,
                                              __HIP_MEMORY_SCOPE_AGENT);
                    if (__all(v >= tgt)) break;
                    __builtin_amdgcn_s_sleep(1);
                }
                if (tid == 0)
                    __builtin_amdgcn_fence(__ATOMIC_ACQUIRE, "agent"); // inv L1/L2
            }
            __syncthreads();
        }
    }
}

extern "C" void kernel_launch(void* const* d_in, const int* in_sizes, int n_in,
                              void* d_out, int out_size, void* d_ws, size_t ws_size,
                              hipStream_t stream) {
    const float* z = (const float*)d_in[0];
    const int* toks = (const int*)d_in[1];
    const float* embed_w = (const float*)d_in[3];
    const float* z2h_w = (const float*)d_in[4];
    const float* z2h_b = (const float*)d_in[5];
    const float* w_ih = (const float*)d_in[6];
    const float* b_ih = (const float*)d_in[7];
    const float* w_hh = (const float*)d_in[8];
    const float* b_hh = (const float*)d_in[9];
    const float* out_w = (const float*)d_in[10];
    const float* out_b = (const float*)d_in[11];
    float* out = (float*)d_out;

    char* ws = (char*)d_ws;
    size_t off = 0;
    auto alloc = [&](size_t bytes) {
        char* p = ws + off;
        off += (bytes + 255) & ~(size_t)255;
        return p;
    };
    u16* Whh_bf = (u16*)alloc(3072ull * 1024 * 2);
    u16* Wout_bf = (u16*)alloc(1024ull * 1024 * 2);
    u16* Wihh_bf = (u16*)alloc(3072ull * 1024 * 2);
    u16* Emb_bf = (u16*)alloc(1024ull * 1024 * 2);
    float* E = (float*)alloc(1024ull * 3072 * 4);
    float* Zih = (float*)alloc(256ull * 3072 * 4);
    float* Zout = (float*)alloc(256ull * 1024 * 4);
    float* hf = (float*)alloc(256ull * 1024 * 4);
    u16* Hx = (u16*)alloc(2ull * 256 * 1024 * 2);
    u32* flags = (u32*)alloc(1024);
    // total ws use ~34.5 MB

    hipMemsetAsync(flags, 0, 1024, stream);
    cast_k<<<2048, 256, 0, stream>>>(w_hh, 1024, 0, 0, Whh_bf, 3072 * 1024);
    cast_k<<<2048, 256, 0, stream>>>(out_w, 1152, 0, 0, Wout_bf, 1024 * 1024);
    cast_k<<<2048, 256, 0, stream>>>(w_ih, 1152, 0, 0, Wihh_bf, 3072 * 1024);
    cast_k<<<1024, 256, 0, stream>>>(embed_w, 1024, 0, 1, Emb_bf, 1024 * 1024);
    smallgemm_k<<<1024, 256, 0, stream>>>(z, z2h_w, 128, 0, z2h_b, nullptr, 0, hf, Hx, 1024);
    smallgemm_k<<<3072, 256, 0, stream>>>(z, w_ih, 1152, 1024, b_ih, b_hh, 2048, Zih, nullptr, 3072);
    smallgemm_k<<<1024, 256, 0, stream>>>(z, out_w, 1152, 1024, out_b, nullptr, 0, Zout, nullptr, 1024);
    egemm_k<<<768, 256, 0, stream>>>(Emb_bf, Wihh_bf, E);

    decoder_k<<<256, 256, 0, stream>>>(Whh_bf, Wout_bf, E, Zih, Zout, b_hh, toks, hf, Hx, out,
                                       flags);
}

// Round 7
// 1756.393 us; speedup vs baseline: 3.6063x; 1.3341x over previous
//
#include <hip/hip_runtime.h>
#include <stdint.h>

// DecoderRNN: B=256, NSTEPS=128, I=128, H=1024, V=1024, teacher-forced GRU.
// Round 7: persistent weight-stationary kernel (r6 structure). Cross-block h
// exchange via SC0|SC1 coherent ops (write-through stores, cache-bypassing
// loads) instead of full agent wb/inv fences. E/toks/weights stay L2-warm.
//   precompute: E = relu(embed_w)@W_ih[:,:H]^T ; Zih2 = z@W_ih[:,H:]^T + b_ih (+b_hh r,z)
//               Zout = z@out_w[:,H:]^T + out_b ; h0 = z@z2h_w^T + z2h_b
//   decoder_k: 256 blocks (1/CU), loop s=0..128.
//     block (rB,c): batch rows 64rB..+63, cols 16c..+15 (all 3 gates + V).
//     W_hh gate-r in REGISTERS (32 bf16x8); gates z,n + Wout slice in LDS
//     persistent. Per step: stage h_s (sc1 loads, dbuf) -> 16 MFMA x 8 iters
//     -> epilogue (h stores sc0 sc1) -> per-row-group flag barrier (no fences).

#define NSTEP 128

typedef unsigned short u16;
typedef unsigned int u32;
typedef __attribute__((ext_vector_type(8))) short bf16x8;
typedef __attribute__((ext_vector_type(4))) float f32x4;

typedef __attribute__((address_space(3))) void lds_void;
typedef const __attribute__((address_space(1))) void glb_void;
#define GLD16(g, l) __builtin_amdgcn_global_load_lds((glb_void*)(g), (lds_void*)(l), 16, 0, 0)
// CPol gfx940+: SC0=1, NT=2, SC1=16 -> sc0|sc1 = 17 (coherent read, bypass L1/L2)
#define GLD16C(g, l) __builtin_amdgcn_global_load_lds((glb_void*)(g), (lds_void*)(l), 16, 0, 17)
#define CFENCE() asm volatile("" ::: "memory")

__device__ __forceinline__ u16 f2bf(float f) {
    u32 u = __float_as_uint(f);
    u = (u + 0x7FFFu + ((u >> 16) & 1u)) >> 16;
    return (u16)u;
}

// coherent 2-byte store: write-through to coherent point (no fence needed)
__device__ __forceinline__ void store_short_coherent(u16* p, u32 v) {
    asm volatile("global_store_short %0, %1, off sc0 sc1" ::"v"(p), "v"(v) : "memory");
}

// ---- elementwise fp32 -> bf16 cast (1024 columns per row) ------------------
__global__ void cast_k(const float* __restrict__ src, int ld, int off, int relu,
                       u16* __restrict__ dst, int n) {
    for (int i = blockIdx.x * blockDim.x + threadIdx.x; i < n; i += gridDim.x * blockDim.x) {
        int row = i >> 10, col = i & 1023;
        float v = src[(long)row * ld + off + col];
        if (relu) v = fmaxf(v, 0.f);
        dst[i] = f2bf(v);
    }
}

// ---- small fp32 GEMM: C[b][n] = z[b]·W[n, off:off+128] + bias[n] (+bias2) --
__global__ void smallgemm_k(const float* __restrict__ z, const float* __restrict__ W,
                            int ldw, int off, const float* __restrict__ bias,
                            const float* __restrict__ bias2, int n2max,
                            float* __restrict__ C, u16* __restrict__ Cbf, int N) {
    int n = blockIdx.x;
    int b = threadIdx.x;
    float acc = bias[n] + ((bias2 && n < n2max) ? bias2[n] : 0.f);
    const float* zr = z + b * 128;
    const float* wr = W + (long)n * ldw + off;
#pragma unroll 8
    for (int k = 0; k < 128; ++k) acc += zr[k] * wr[k];
    C[b * N + n] = acc;
    if (Cbf) Cbf[b * N + n] = f2bf(acc);
}

// ---- E table GEMM: E[v][n] = relu(embed)[v]·Wihh[n]  (M=1024,N=3072,K=1024)
__global__ __launch_bounds__(256) void egemm_k(const u16* __restrict__ A,
                                               const u16* __restrict__ W,
                                               float* __restrict__ C) {
    __shared__ __align__(16) u16 lds[2][160 * 64];
    int tid = threadIdx.x, lane = tid & 63, wv = tid >> 6;
    int r0 = (blockIdx.x & 31) * 32;
    int n0 = (blockIdx.x >> 5) * 128;

    f32x4 acc[2][2];
#pragma unroll
    for (int m = 0; m < 2; ++m)
#pragma unroll
        for (int n = 0; n < 2; ++n) acc[m][n] = (f32x4){0.f, 0.f, 0.f, 0.f};

    auto stage = [&](int k0, int bufi) {
#pragma unroll
        for (int r = 0; r < 5; ++r) {
            int L = r * 256 + tid;
            int row = L >> 3;
            int c4 = (L & 7) ^ (row & 7);
            const u16* src = (row < 32)
                                 ? A + (long)(r0 + row) * 1024 + k0 + c4 * 8
                                 : W + (long)(n0 + row - 32) * 1024 + k0 + c4 * 8;
            GLD16(src, &lds[bufi][L * 8]);
        }
    };
    stage(0, 0);
    stage(64, 1);
    for (int it = 0; it < 16; ++it) {
        if (it < 15) asm volatile("s_waitcnt vmcnt(5)" ::: "memory");
        else         asm volatile("s_waitcnt vmcnt(0)" ::: "memory");
        __builtin_amdgcn_s_barrier();
        const char* base = (const char*)&lds[it & 1][0];
        bf16x8 af[2][2], bfr[2][2];
#pragma unroll
        for (int ks = 0; ks < 2; ++ks)
#pragma unroll
            for (int q = 0; q < 2; ++q) {
                int kb = ks * 64 + ((lane >> 4) << 4);
                int rowa = q * 16 + (lane & 15);
                af[ks][q] = *(const bf16x8*)(base + rowa * 128 + (kb ^ ((rowa & 7) << 4)));
                int rowb = 32 + wv * 32 + q * 16 + (lane & 15);
                bfr[ks][q] = *(const bf16x8*)(base + rowb * 128 + (kb ^ ((rowb & 7) << 4)));
            }
#pragma unroll
        for (int ks = 0; ks < 2; ++ks)
#pragma unroll
            for (int m = 0; m < 2; ++m)
#pragma unroll
                for (int n = 0; n < 2; ++n)
                    acc[m][n] = __builtin_amdgcn_mfma_f32_16x16x32_bf16(af[ks][m], bfr[ks][n],
                                                                        acc[m][n], 0, 0, 0);
        asm volatile("s_waitcnt lgkmcnt(0)" ::: "memory");
        __builtin_amdgcn_s_barrier();
        if (it + 2 < 16) stage((it + 2) * 64, it & 1);
    }
#pragma unroll
    for (int m = 0; m < 2; ++m)
#pragma unroll
        for (int n = 0; n < 2; ++n)
#pragma unroll
            for (int r = 0; r < 4; ++r) {
                int row = r0 + m * 16 + ((lane >> 4) << 2) + r;
                int col = n0 + wv * 32 + n * 16 + (lane & 15);
                C[(long)row * 3072 + col] = acc[m][n][r];
            }
}

// ---- persistent decoder ----------------------------------------------------
// LDS layout (bytes), 131072 total:
//   [0, 65536)        W12: gates z,n  [32 rows][1024 k], row stride 2048 B
//   [65536, 98304)    WoutL: [16 rows][1024 k], row stride 2048 B (persistent)
//   [98304, 131072)   dbuf: 2 x 16384 B: [64 rows][128 k], row stride 256 B
//   (startup: gate-r slice [16][1024] temporarily in dbuf region -> regs)
__global__ __launch_bounds__(256, 1) void decoder_k(
    const u16* __restrict__ Whh,    // [3072][1024] bf16
    const u16* __restrict__ Wout,   // [1024][1024] bf16
    const float* __restrict__ E,    // [1024][3072]
    const float* __restrict__ Zih2, // [256][3072]  (b_ih folded; +b_hh for r,z)
    const float* __restrict__ Zout, // [256][1024]  (out_b folded)
    const float* __restrict__ bhh,  // [3072]
    const int* __restrict__ toks,   // [128][256]
    const float* __restrict__ h0f,  // [256][1024] fp32
    u16* __restrict__ Hx,           // [2][256][1024] bf16 ping-pong
    float* __restrict__ out,        // [256][128][1024]
    u32* __restrict__ flags) {      // [256] per-block step flags
    __shared__ __align__(16) char L[131072];
    const int tid = threadIdx.x, lane = tid & 63, wv = tid >> 6;
    const int bid = blockIdx.x;
    const int rB = bid >> 6; // rows rB*64..+63
    const int c = bid & 63;  // cols c*16..+15

    // ---- startup staging: gate-r -> tmp(dbuf), gates z,n -> W12, Wout -> WoutL
#pragma unroll
    for (int r = 0; r < 8; ++r) {
        int l = r * 256 + tid, row = l >> 7, ck = (l & 127) ^ (row & 15);
        GLD16(Whh + (long)(c * 16 + row) * 1024 + ck * 8, &L[98304 + l * 16]);
    }
#pragma unroll
    for (int r = 0; r < 16; ++r) {
        int l = r * 256 + tid, row = l >> 7, ck = (l & 127) ^ (row & 15);
        GLD16(Whh + (long)((1 + (row >> 4)) * 1024 + c * 16 + (row & 15)) * 1024 + ck * 8,
              &L[l * 16]);
    }
#pragma unroll
    for (int r = 0; r < 8; ++r) {
        int l = r * 256 + tid, row = l >> 7, ck = (l & 127) ^ (row & 15);
        GLD16(Wout + (long)(c * 16 + row) * 1024 + ck * 8, &L[65536 + l * 16]);
    }
    asm volatile("s_waitcnt vmcnt(0)" ::: "memory");
    __builtin_amdgcn_s_barrier();
    bf16x8 w0[32]; // gate-r B-fragments, [it*4+ks], persistent in VGPRs
#pragma unroll
    for (int it = 0; it < 8; ++it)
#pragma unroll
        for (int ks = 0; ks < 4; ++ks) {
            int row = lane & 15, kc = it * 16 + ks * 4 + (lane >> 4);
            w0[it * 4 + ks] = *(const bf16x8*)(L + 98304 + row * 2048 + ((kc ^ row) << 4));
        }
    asm volatile("s_waitcnt lgkmcnt(0)" ::: "memory");
    __builtin_amdgcn_s_barrier();

    // ---- per-thread step-invariant state
    const int bbase = rB * 64 + wv * 16 + ((lane >> 4) << 2); // 4 rows bbase..+3
    const int j = c * 16 + (lane & 15);
    const float bhn = bhh[2048 + j];
    float hprev[4], zi0[4], zi1[4], zi2[4], zo[4];
#pragma unroll
    for (int r = 0; r < 4; ++r) {
        int b = bbase + r;
        hprev[r] = h0f[b * 1024 + j];
        zi0[r] = Zih2[(long)b * 3072 + j];
        zi1[r] = Zih2[(long)b * 3072 + 1024 + j];
        zi2[r] = Zih2[(long)b * 3072 + 2048 + j];
        zo[r] = Zout[b * 1024 + j];
    }

    for (int s = 0; s <= NSTEP; ++s) {
        // tokens (consumed in epilogue); pinned before stages (older in vmcnt queue
        // -> in-loop waits are only over-strict, never under-strict)
        int tok[4];
#pragma unroll
        for (int r = 0; r < 4; ++r)
            tok[r] = (s == 0) ? 0 : toks[(s - 1) * 256 + bbase + r];
        CFENCE();

        const u16* hsrc = Hx + (size_t)(s & 1) * 262144;
        auto stage = [&](int ch) {
            char* dst = L + 98304 + (ch & 1) * 16384;
            int k0 = ch * 128;
#pragma unroll
            for (int r = 0; r < 4; ++r) {
                int l = r * 256 + tid, row = l >> 4, ck = (l & 15) ^ (row & 15);
                GLD16C(hsrc + (long)(rB * 64 + row) * 1024 + k0 + ck * 8, dst + l * 16);
            }
        };
        stage(0);
        stage(1);
        CFENCE();

        f32x4 a0 = {0.f, 0.f, 0.f, 0.f}, a1 = a0, a2 = a0, aO = a0;
#pragma unroll
        for (int it = 0; it < 8; ++it) {
            // conservative schedule: leave exactly next-stage (4 loads) in flight
            if (it < 7) asm volatile("s_waitcnt vmcnt(4)" ::: "memory");
            else        asm volatile("s_waitcnt vmcnt(0)" ::: "memory");
            __builtin_amdgcn_s_barrier();
            const char* Ab = L + 98304 + (it & 1) * 16384;
            bf16x8 af[4];
#pragma unroll
            for (int ks = 0; ks < 4; ++ks) {
                int row = wv * 16 + (lane & 15), kc = ks * 4 + (lane >> 4);
                af[ks] = *(const bf16x8*)(Ab + row * 256 + ((kc ^ (row & 15)) << 4));
            }
#pragma unroll
            for (int ks = 0; ks < 4; ++ks) // gate r from registers
                a0 = __builtin_amdgcn_mfma_f32_16x16x32_bf16(af[ks], w0[it * 4 + ks], a0, 0, 0, 0);
#pragma unroll
            for (int ks = 0; ks < 4; ++ks) { // gate z from W12
                int row = lane & 15, kc = it * 16 + ks * 4 + (lane >> 4);
                bf16x8 wg = *(const bf16x8*)(L + row * 2048 + ((kc ^ row) << 4));
                a1 = __builtin_amdgcn_mfma_f32_16x16x32_bf16(af[ks], wg, a1, 0, 0, 0);
            }
#pragma unroll
            for (int ks = 0; ks < 4; ++ks) { // gate n from W12
                int row = 16 + (lane & 15), kc = it * 16 + ks * 4 + (lane >> 4);
                bf16x8 wg = *(const bf16x8*)(L + row * 2048 + ((kc ^ (row & 15)) << 4));
                a2 = __builtin_amdgcn_mfma_f32_16x16x32_bf16(af[ks], wg, a2, 0, 0, 0);
            }
#pragma unroll
            for (int ks = 0; ks < 4; ++ks) { // OUT from WoutL (persistent)
                int row = lane & 15, kc = it * 16 + ks * 4 + (lane >> 4);
                bf16x8 wo = *(const bf16x8*)(L + 65536 + row * 2048 + ((kc ^ row) << 4));
                aO = __builtin_amdgcn_mfma_f32_16x16x32_bf16(af[ks], wo, aO, 0, 0, 0);
            }
            asm volatile("s_waitcnt lgkmcnt(0)" ::: "memory");
            __builtin_amdgcn_s_barrier();
            if (it < 6) stage(it + 2);
        }

        if (s < NSTEP) { // GRU epilogue -> h_{s+1}; coherent write-through stores
            u16* hdst = Hx + (size_t)((s + 1) & 1) * 262144;
#pragma unroll
            for (int r = 0; r < 4; ++r) {
                int b = bbase + r;
                long eb = (long)tok[r] * 3072 + j;
                float rg = 1.f / (1.f + expf(-(E[eb] + zi0[r] + a0[r])));
                float zg = 1.f / (1.f + expf(-(E[eb + 1024] + zi1[r] + a1[r])));
                float nn = tanhf(E[eb + 2048] + zi2[r] + rg * (a2[r] + bhn));
                float hv = (1.f - zg) * nn + zg * hprev[r];
                hprev[r] = hv;
                store_short_coherent(hdst + b * 1024 + j, (u32)f2bf(hv));
            }
        }
        if (s >= 1) { // OUT epilogue -> o_{s-1} (plain stores, flushed at kernel end)
#pragma unroll
            for (int r = 0; r < 4; ++r)
                out[(long)(bbase + r) * 131072 + (long)(s - 1) * 1024 + j] = aO[r] + zo[r];
        }
        if (s < NSTEP) {
            // per-row-group barrier: 64 blocks sharing rB exchange h rows.
            // h went out via sc0|sc1 write-through; vmcnt(0) = committed at the
            // coherent point; flag store (agent atomic) is issued strictly after.
            asm volatile("s_waitcnt vmcnt(0)" ::: "memory");
            __syncthreads();
            if (tid < 64) { // wave 0
                if (tid == 0)
                    __hip_atomic_store(&flags[bid], (u32)(s + 1), __ATOMIC_RELAXED,
                                       __HIP_MEMORY_SCOPE_AGENT);
                const u32 tgt = (u32)(s + 1);
                const u32* gf = flags + (rB << 6);
                while (true) {
                    u32 v = __hip_atomic_load(&gf[tid], __ATOMIC_RELAXED,
                                              __HIP_MEMORY_SCOPE_AGENT);
                    if (__all(v >= tgt)) break;
                    __builtin_amdgcn_s_sleep(1);
                }
            }
            __syncthreads();
        }
    }
}

extern "C" void kernel_launch(void* const* d_in, const int* in_sizes, int n_in,
                              void* d_out, int out_size, void* d_ws, size_t ws_size,
                              hipStream_t stream) {
    const float* z = (const float*)d_in[0];
    const int* toks = (const int*)d_in[1];
    const float* embed_w = (const float*)d_in[3];
    const float* z2h_w = (const float*)d_in[4];
    const float* z2h_b = (const float*)d_in[5];
    const float* w_ih = (const float*)d_in[6];
    const float* b_ih = (const float*)d_in[7];
    const float* w_hh = (const float*)d_in[8];
    const float* b_hh = (const float*)d_in[9];
    const float* out_w = (const float*)d_in[10];
    const float* out_b = (const float*)d_in[11];
    float* out = (float*)d_out;

    char* ws = (char*)d_ws;
    size_t off = 0;
    auto alloc = [&](size_t bytes) {
        char* p = ws + off;
        off += (bytes + 255) & ~(size_t)255;
        return p;
    };
    u16* Whh_bf = (u16*)alloc(3072ull * 1024 * 2);
    u16* Wout_bf = (u16*)alloc(1024ull * 1024 * 2);
    u16* Wihh_bf = (u16*)alloc(3072ull * 1024 * 2);
    u16* Emb_bf = (u16*)alloc(1024ull * 1024 * 2);
    float* E = (float*)alloc(1024ull * 3072 * 4);
    float* Zih = (float*)alloc(256ull * 3072 * 4);
    float* Zout = (float*)alloc(256ull * 1024 * 4);
    float* hf = (float*)alloc(256ull * 1024 * 4);
    u16* Hx = (u16*)alloc(2ull * 256 * 1024 * 2);
    u32* flags = (u32*)alloc(1024);
    // total ws use ~34.5 MB

    hipMemsetAsync(flags, 0, 1024, stream);
    cast_k<<<2048, 256, 0, stream>>>(w_hh, 1024, 0, 0, Whh_bf, 3072 * 1024);
    cast_k<<<2048, 256, 0, stream>>>(out_w, 1152, 0, 0, Wout_bf, 1024 * 1024);
    cast_k<<<2048, 256, 0, stream>>>(w_ih, 1152, 0, 0, Wihh_bf, 3072 * 1024);
    cast_k<<<1024, 256, 0, stream>>>(embed_w, 1024, 0, 1, Emb_bf, 1024 * 1024);
    smallgemm_k<<<1024, 256, 0, stream>>>(z, z2h_w, 128, 0, z2h_b, nullptr, 0, hf, Hx, 1024);
    smallgemm_k<<<3072, 256, 0, stream>>>(z, w_ih, 1152, 1024, b_ih, b_hh, 2048, Zih, nullptr, 3072);
    smallgemm_k<<<1024, 256, 0, stream>>>(z, out_w, 1152, 1024, out_b, nullptr, 0, Zout, nullptr, 1024);
    egemm_k<<<768, 256, 0, stream>>>(Emb_bf, Wihh_bf, E);

    decoder_k<<<256, 256, 0, stream>>>(Whh_bf, Wout_bf, E, Zih, Zout, b_hh, toks, hf, Hx, out,
                                       flags);
}

// Round 8
// 1412.701 us; speedup vs baseline: 4.4836x; 1.2433x over previous
//
#include <hip/hip_runtime.h>
#include <stdint.h>

// DecoderRNN: B=256, NSTEPS=128, I=128, H=1024, V=1024, teacher-forced GRU.
// Round 8: r7 structure + (1) 4-deep chunk pipeline (LDS 160KB exactly),
// (2) E-gather issued at step top (position-independent vmcnt schedule),
// (3) raw s_barrier exchange with partial vmcnt drain (OUT stores hidden
// under the flag poll).
//   decoder_k: 256 blocks (1/CU), loop s=0..128.
//     block (rB,c): batch rows 64rB..+63, cols 16c..+15 (3 gates + V).
//     W_hh gate-r in REGISTERS (32 bf16x8); gates z,n (64KB) + Wout (32KB) in
//     LDS persistent; h staged per step through 4x16KB LDS chunks (sc0|sc1
//     coherent loads). h written back via sc0|sc1 write-through stores.
//     Cross-block sync: per-row-group flag store + relaxed poll (r7-proven).

#define NSTEP 128

typedef unsigned short u16;
typedef unsigned int u32;
typedef __attribute__((ext_vector_type(8))) short bf16x8;
typedef __attribute__((ext_vector_type(4))) float f32x4;

typedef __attribute__((address_space(3))) void lds_void;
typedef const __attribute__((address_space(1))) void glb_void;
#define GLD16(g, l) __builtin_amdgcn_global_load_lds((glb_void*)(g), (lds_void*)(l), 16, 0, 0)
// CPol gfx940+: SC0=1, SC1=16 -> 17 (coherent read, bypass L1/L2)
#define GLD16C(g, l) __builtin_amdgcn_global_load_lds((glb_void*)(g), (lds_void*)(l), 16, 0, 17)
#define CFENCE() asm volatile("" ::: "memory")

__device__ __forceinline__ u16 f2bf(float f) {
    u32 u = __float_as_uint(f);
    u = (u + 0x7FFFu + ((u >> 16) & 1u)) >> 16;
    return (u16)u;
}

// coherent 2-byte store: write-through to coherent point
__device__ __forceinline__ void store_short_coherent(u16* p, u32 v) {
    asm volatile("global_store_short %0, %1, off sc0 sc1" ::"v"(p), "v"(v) : "memory");
}

// ---- elementwise fp32 -> bf16 cast (1024 columns per row) ------------------
__global__ void cast_k(const float* __restrict__ src, int ld, int off, int relu,
                       u16* __restrict__ dst, int n) {
    for (int i = blockIdx.x * blockDim.x + threadIdx.x; i < n; i += gridDim.x * blockDim.x) {
        int row = i >> 10, col = i & 1023;
        float v = src[(long)row * ld + off + col];
        if (relu) v = fmaxf(v, 0.f);
        dst[i] = f2bf(v);
    }
}

// ---- small fp32 GEMM: C[b][n] = z[b]·W[n, off:off+128] + bias[n] (+bias2) --
__global__ void smallgemm_k(const float* __restrict__ z, const float* __restrict__ W,
                            int ldw, int off, const float* __restrict__ bias,
                            const float* __restrict__ bias2, int n2max,
                            float* __restrict__ C, u16* __restrict__ Cbf, int N) {
    int n = blockIdx.x;
    int b = threadIdx.x;
    float acc = bias[n] + ((bias2 && n < n2max) ? bias2[n] : 0.f);
    const float* zr = z + b * 128;
    const float* wr = W + (long)n * ldw + off;
#pragma unroll 8
    for (int k = 0; k < 128; ++k) acc += zr[k] * wr[k];
    C[b * N + n] = acc;
    if (Cbf) Cbf[b * N + n] = f2bf(acc);
}

// ---- E table GEMM: E[v][n] = relu(embed)[v]·Wihh[n]  (M=1024,N=3072,K=1024)
__global__ __launch_bounds__(256) void egemm_k(const u16* __restrict__ A,
                                               const u16* __restrict__ W,
                                               float* __restrict__ C) {
    __shared__ __align__(16) u16 lds[2][160 * 64];
    int tid = threadIdx.x, lane = tid & 63, wv = tid >> 6;
    int r0 = (blockIdx.x & 31) * 32;
    int n0 = (blockIdx.x >> 5) * 128;

    f32x4 acc[2][2];
#pragma unroll
    for (int m = 0; m < 2; ++m)
#pragma unroll
        for (int n = 0; n < 2; ++n) acc[m][n] = (f32x4){0.f, 0.f, 0.f, 0.f};

    auto stage = [&](int k0, int bufi) {
#pragma unroll
        for (int r = 0; r < 5; ++r) {
            int L = r * 256 + tid;
            int row = L >> 3;
            int c4 = (L & 7) ^ (row & 7);
            const u16* src = (row < 32)
                                 ? A + (long)(r0 + row) * 1024 + k0 + c4 * 8
                                 : W + (long)(n0 + row - 32) * 1024 + k0 + c4 * 8;
            GLD16(src, &lds[bufi][L * 8]);
        }
    };
    stage(0, 0);
    stage(64, 1);
    for (int it = 0; it < 16; ++it) {
        if (it < 15) asm volatile("s_waitcnt vmcnt(5)" ::: "memory");
        else         asm volatile("s_waitcnt vmcnt(0)" ::: "memory");
        __builtin_amdgcn_s_barrier();
        const char* base = (const char*)&lds[it & 1][0];
        bf16x8 af[2][2], bfr[2][2];
#pragma unroll
        for (int ks = 0; ks < 2; ++ks)
#pragma unroll
            for (int q = 0; q < 2; ++q) {
                int kb = ks * 64 + ((lane >> 4) << 4);
                int rowa = q * 16 + (lane & 15);
                af[ks][q] = *(const bf16x8*)(base + rowa * 128 + (kb ^ ((rowa & 7) << 4)));
                int rowb = 32 + wv * 32 + q * 16 + (lane & 15);
                bfr[ks][q] = *(const bf16x8*)(base + rowb * 128 + (kb ^ ((rowb & 7) << 4)));
            }
#pragma unroll
        for (int ks = 0; ks < 2; ++ks)
#pragma unroll
            for (int m = 0; m < 2; ++m)
#pragma unroll
                for (int n = 0; n < 2; ++n)
                    acc[m][n] = __builtin_amdgcn_mfma_f32_16x16x32_bf16(af[ks][m], bfr[ks][n],
                                                                        acc[m][n], 0, 0, 0);
        asm volatile("s_waitcnt lgkmcnt(0)" ::: "memory");
        __builtin_amdgcn_s_barrier();
        if (it + 2 < 16) stage((it + 2) * 64, it & 1);
    }
#pragma unroll
    for (int m = 0; m < 2; ++m)
#pragma unroll
        for (int n = 0; n < 2; ++n)
#pragma unroll
            for (int r = 0; r < 4; ++r) {
                int row = r0 + m * 16 + ((lane >> 4) << 2) + r;
                int col = n0 + wv * 32 + n * 16 + (lane & 15);
                C[(long)row * 3072 + col] = acc[m][n][r];
            }
}

// ---- persistent decoder ----------------------------------------------------
// LDS layout (bytes), 163840 total (full 160 KiB):
//   [0, 65536)         W12: gates z,n  [32 rows][1024 k], row stride 2048 B
//   [65536, 98304)     WoutL: [16 rows][1024 k], row stride 2048 B (persistent)
//   [98304, 163840)    dbuf: 4 x 16384 B: [64 rows][128 k], row stride 256 B
//   (startup: gate-r slice [16][1024] temporarily in dbuf region -> regs)
__global__ __launch_bounds__(256, 1) void decoder_k(
    const u16* __restrict__ Whh,    // [3072][1024] bf16
    const u16* __restrict__ Wout,   // [1024][1024] bf16
    const float* __restrict__ E,    // [1024][3072]
    const float* __restrict__ Zih2, // [256][3072]  (b_ih folded; +b_hh for r,z)
    const float* __restrict__ Zout, // [256][1024]  (out_b folded)
    const float* __restrict__ bhh,  // [3072]
    const int* __restrict__ toks,   // [128][256]
    const float* __restrict__ h0f,  // [256][1024] fp32
    u16* __restrict__ Hx,           // [2][256][1024] bf16 ping-pong
    float* __restrict__ out,        // [256][128][1024]
    u32* __restrict__ flags) {      // [256] per-block step flags
    __shared__ __align__(16) char L[163840];
    const int tid = threadIdx.x, lane = tid & 63, wv = tid >> 6;
    const int bid = blockIdx.x;
    const int rB = bid >> 6; // rows rB*64..+63
    const int c = bid & 63;  // cols c*16..+15

    // ---- startup staging: gate-r -> tmp(dbuf), gates z,n -> W12, Wout -> WoutL
#pragma unroll
    for (int r = 0; r < 8; ++r) {
        int l = r * 256 + tid, row = l >> 7, ck = (l & 127) ^ (row & 15);
        GLD16(Whh + (long)(c * 16 + row) * 1024 + ck * 8, &L[98304 + l * 16]);
    }
#pragma unroll
    for (int r = 0; r < 16; ++r) {
        int l = r * 256 + tid, row = l >> 7, ck = (l & 127) ^ (row & 15);
        GLD16(Whh + (long)((1 + (row >> 4)) * 1024 + c * 16 + (row & 15)) * 1024 + ck * 8,
              &L[l * 16]);
    }
#pragma unroll
    for (int r = 0; r < 8; ++r) {
        int l = r * 256 + tid, row = l >> 7, ck = (l & 127) ^ (row & 15);
        GLD16(Wout + (long)(c * 16 + row) * 1024 + ck * 8, &L[65536 + l * 16]);
    }
    asm volatile("s_waitcnt vmcnt(0)" ::: "memory");
    __builtin_amdgcn_s_barrier();
    bf16x8 w0[32]; // gate-r B-fragments, [it*4+ks], persistent in VGPRs
#pragma unroll
    for (int it = 0; it < 8; ++it)
#pragma unroll
        for (int ks = 0; ks < 4; ++ks) {
            int row = lane & 15, kc = it * 16 + ks * 4 + (lane >> 4);
            w0[it * 4 + ks] = *(const bf16x8*)(L + 98304 + row * 2048 + ((kc ^ row) << 4));
        }
    asm volatile("s_waitcnt lgkmcnt(0)" ::: "memory");
    __builtin_amdgcn_s_barrier();

    // ---- per-thread step-invariant state
    const int bbase = rB * 64 + wv * 16 + ((lane >> 4) << 2); // 4 rows bbase..+3
    const int j = c * 16 + (lane & 15);
    const float bhn = bhh[2048 + j];
    float hprev[4], zi0[4], zi1[4], zi2[4], zo[4];
#pragma unroll
    for (int r = 0; r < 4; ++r) {
        int b = bbase + r;
        hprev[r] = h0f[b * 1024 + j];
        zi0[r] = Zih2[(long)b * 3072 + j];
        zi1[r] = Zih2[(long)b * 3072 + 1024 + j];
        zi2[r] = Zih2[(long)b * 3072 + 2048 + j];
        zo[r] = Zout[b * 1024 + j];
    }

    for (int s = 0; s <= NSTEP; ++s) {
        // ---- step top: tok -> E gather (consumed only in epilogue; its
        // latency runs concurrent with the whole K-loop)
        int tok[4];
#pragma unroll
        for (int r = 0; r < 4; ++r)
            tok[r] = (s == 0) ? 0 : toks[(s - 1) * 256 + bbase + r];
        CFENCE();
        float e0[4], e1[4], e2[4];
#pragma unroll
        for (int r = 0; r < 4; ++r) {
            long eb = (long)tok[r] * 3072 + j;
            e0[r] = E[eb];
            e1[r] = E[eb + 1024];
            e2[r] = E[eb + 2048];
        }
        CFENCE();

        const u16* hsrc = Hx + (size_t)(s & 1) * 262144;
        auto stage = [&](int ch) {
            char* dst = L + 98304 + (ch & 3) * 16384;
            int k0 = ch * 128;
#pragma unroll
            for (int r = 0; r < 4; ++r) {
                int l = r * 256 + tid, row = l >> 4, ck = (l & 15) ^ (row & 15);
                GLD16C(hsrc + (long)(rB * 64 + row) * 1024 + k0 + ck * 8, dst + l * 16);
            }
        };
        stage(0);
        stage(1);
        stage(2);
        stage(3);
        CFENCE();

        f32x4 a0 = {0.f, 0.f, 0.f, 0.f}, a1 = a0, a2 = a0, aO = a0;
#pragma unroll
        for (int it = 0; it < 8; ++it) {
            // wait = 4 * (#stage chunks newer than chunk `it`): safe regardless
            // of tok/E queue position (they can only make the wait stricter)
            if (it < 5)       asm volatile("s_waitcnt vmcnt(12)" ::: "memory");
            else if (it == 5) asm volatile("s_waitcnt vmcnt(8)" ::: "memory");
            else if (it == 6) asm volatile("s_waitcnt vmcnt(4)" ::: "memory");
            else              asm volatile("s_waitcnt vmcnt(0)" ::: "memory");
            __builtin_amdgcn_s_barrier();
            const char* Ab = L + 98304 + (it & 3) * 16384;
            bf16x8 af[4];
#pragma unroll
            for (int ks = 0; ks < 4; ++ks) {
                int row = wv * 16 + (lane & 15), kc = ks * 4 + (lane >> 4);
                af[ks] = *(const bf16x8*)(Ab + row * 256 + ((kc ^ (row & 15)) << 4));
            }
#pragma unroll
            for (int ks = 0; ks < 4; ++ks) // gate r from registers
                a0 = __builtin_amdgcn_mfma_f32_16x16x32_bf16(af[ks], w0[it * 4 + ks], a0, 0, 0, 0);
#pragma unroll
            for (int ks = 0; ks < 4; ++ks) { // gate z from W12
                int row = lane & 15, kc = it * 16 + ks * 4 + (lane >> 4);
                bf16x8 wg = *(const bf16x8*)(L + row * 2048 + ((kc ^ row) << 4));
                a1 = __builtin_amdgcn_mfma_f32_16x16x32_bf16(af[ks], wg, a1, 0, 0, 0);
            }
#pragma unroll
            for (int ks = 0; ks < 4; ++ks) { // gate n from W12
                int row = 16 + (lane & 15), kc = it * 16 + ks * 4 + (lane >> 4);
                bf16x8 wg = *(const bf16x8*)(L + row * 2048 + ((kc ^ (row & 15)) << 4));
                a2 = __builtin_amdgcn_mfma_f32_16x16x32_bf16(af[ks], wg, a2, 0, 0, 0);
            }
#pragma unroll
            for (int ks = 0; ks < 4; ++ks) { // OUT from WoutL (persistent)
                int row = lane & 15, kc = it * 16 + ks * 4 + (lane >> 4);
                bf16x8 wo = *(const bf16x8*)(L + 65536 + row * 2048 + ((kc ^ row) << 4));
                aO = __builtin_amdgcn_mfma_f32_16x16x32_bf16(af[ks], wo, aO, 0, 0, 0);
            }
            asm volatile("s_waitcnt lgkmcnt(0)" ::: "memory");
            __builtin_amdgcn_s_barrier();
            if (it < 4) stage(it + 4);
        }

        if (s < NSTEP) { // GRU epilogue -> h_{s+1}; coherent write-through stores
            u16* hdst = Hx + (size_t)((s + 1) & 1) * 262144;
#pragma unroll
            for (int r = 0; r < 4; ++r) {
                int b = bbase + r;
                float rg = 1.f / (1.f + expf(-(e0[r] + zi0[r] + a0[r])));
                float zg = 1.f / (1.f + expf(-(e1[r] + zi1[r] + a1[r])));
                float nn = tanhf(e2[r] + zi2[r] + rg * (a2[r] + bhn));
                float hv = (1.f - zg) * nn + zg * hprev[r];
                hprev[r] = hv;
                store_short_coherent(hdst + b * 1024 + j, (u32)f2bf(hv));
            }
        }
        CFENCE();
        if (s >= 1) { // OUT epilogue (plain stores; drain during flag poll)
#pragma unroll
            for (int r = 0; r < 4; ++r)
                out[(long)(bbase + r) * 131072 + (long)(s - 1) * 1024 + j] = aO[r] + zo[r];
        }
        CFENCE();
        if (s < NSTEP) {
            // exchange: retire h stores only (4 newest = OUT stores may remain),
            // raw s_barrier (no implicit vmcnt(0) drain), flag + relaxed poll.
            if (s >= 1) asm volatile("s_waitcnt vmcnt(4)" ::: "memory");
            else        asm volatile("s_waitcnt vmcnt(0)" ::: "memory");
            __builtin_amdgcn_s_barrier();
            if (tid < 64) { // wave 0
                if (tid == 0)
                    __hip_atomic_store(&flags[bid], (u32)(s + 1), __ATOMIC_RELAXED,
                                       __HIP_MEMORY_SCOPE_AGENT);
                const u32 tgt = (u32)(s + 1);
                const u32* gf = flags + (rB << 6);
                while (true) {
                    u32 v = __hip_atomic_load(&gf[tid], __ATOMIC_RELAXED,
                                              __HIP_MEMORY_SCOPE_AGENT);
                    if (__all(v >= tgt)) break;
                    __builtin_amdgcn_s_sleep(1);
                }
            }
            __builtin_amdgcn_s_barrier();
        }
    }
}

extern "C" void kernel_launch(void* const* d_in, const int* in_sizes, int n_in,
                              void* d_out, int out_size, void* d_ws, size_t ws_size,
                              hipStream_t stream) {
    const float* z = (const float*)d_in[0];
    const int* toks = (const int*)d_in[1];
    const float* embed_w = (const float*)d_in[3];
    const float* z2h_w = (const float*)d_in[4];
    const float* z2h_b = (const float*)d_in[5];
    const float* w_ih = (const float*)d_in[6];
    const float* b_ih = (const float*)d_in[7];
    const float* w_hh = (const float*)d_in[8];
    const float* b_hh = (const float*)d_in[9];
    const float* out_w = (const float*)d_in[10];
    const float* out_b = (const float*)d_in[11];
    float* out = (float*)d_out;

    char* ws = (char*)d_ws;
    size_t off = 0;
    auto alloc = [&](size_t bytes) {
        char* p = ws + off;
        off += (bytes + 255) & ~(size_t)255;
        return p;
    };
    u16* Whh_bf = (u16*)alloc(3072ull * 1024 * 2);
    u16* Wout_bf = (u16*)alloc(1024ull * 1024 * 2);
    u16* Wihh_bf = (u16*)alloc(3072ull * 1024 * 2);
    u16* Emb_bf = (u16*)alloc(1024ull * 1024 * 2);
    float* E = (float*)alloc(1024ull * 3072 * 4);
    float* Zih = (float*)alloc(256ull * 3072 * 4);
    float* Zout = (float*)alloc(256ull * 1024 * 4);
    float* hf = (float*)alloc(256ull * 1024 * 4);
    u16* Hx = (u16*)alloc(2ull * 256 * 1024 * 2);
    u32* flags = (u32*)alloc(1024);
    // total ws use ~34.5 MB

    hipMemsetAsync(flags, 0, 1024, stream);
    cast_k<<<2048, 256, 0, stream>>>(w_hh, 1024, 0, 0, Whh_bf, 3072 * 1024);
    cast_k<<<2048, 256, 0, stream>>>(out_w, 1152, 0, 0, Wout_bf, 1024 * 1024);
    cast_k<<<2048, 256, 0, stream>>>(w_ih, 1152, 0, 0, Wihh_bf, 3072 * 1024);
    cast_k<<<1024, 256, 0, stream>>>(embed_w, 1024, 0, 1, Emb_bf, 1024 * 1024);
    smallgemm_k<<<1024, 256, 0, stream>>>(z, z2h_w, 128, 0, z2h_b, nullptr, 0, hf, Hx, 1024);
    smallgemm_k<<<3072, 256, 0, stream>>>(z, w_ih, 1152, 1024, b_ih, b_hh, 2048, Zih, nullptr, 3072);
    smallgemm_k<<<1024, 256, 0, stream>>>(z, out_w, 1152, 1024, out_b, nullptr, 0, Zout, nullptr, 1024);
    egemm_k<<<768, 256, 0, stream>>>(Emb_bf, Wihh_bf, E);

    decoder_k<<<256, 256, 0, stream>>>(Whh_bf, Wout_bf, E, Zih, Zout, b_hh, toks, hf, Hx, out,
                                       flags);
}